// Round 6
// baseline (29.735 us; speedup 1.0000x reference)
//
#include <hip/hip_runtime.h>
#include <math.h>

// forecast (32,20,96,96) f32, truth (32,96,96) f32 -> scalar f32
#define M_ENS 20
#define HW    9216            // 96*96 pixels per image
#define BHWf  294912.0f
#define BLOCK 256
#define BPI   36              // blocks per image: 36*256 == 9216 exact
#define NB    1152            // 36*32 blocks

__global__ void __launch_bounds__(BLOCK)
crps_onepass_kernel(const float* __restrict__ forecast,
                    const float* __restrict__ truth,
                    float* __restrict__ partial,          // NB floats (d_ws)
                    unsigned int* __restrict__ counter,   // monotone ticket (d_ws)
                    float* __restrict__ out) {
    int b  = blockIdx.y;                             // image index 0..31
    int hw = blockIdx.x * BLOCK + threadIdx.x;       // pixel in image, exact cover
    const float* fp = forecast + (size_t)b * (M_ENS * HW) + hw;

    float x[M_ENS];
    #pragma unroll
    for (int e = 0; e < M_ENS; ++e) x[e] = fp[e * HW];
    float y = truth[b * HW + hw];

    float dxy = 0.0f, sum = 0.0f;
    #pragma unroll
    for (int e = 0; e < M_ENS; ++e) {
        dxy += fabsf(x[e] - y);
        sum += x[e];
    }

    float tri = 0.0f;                                // upper-triangle pair sum
    #pragma unroll
    for (int i = 0; i < M_ENS; ++i) {
        #pragma unroll
        for (int j = i + 1; j < M_ENS; ++j) {
            tri += fabsf(x[i] - x[j]);
        }
    }

    float mean = sum * (1.0f / M_ENS);
    float var = 0.0f;
    #pragma unroll
    for (int e = 0; e < M_ENS; ++e) {
        float d = x[e] - mean;
        var += d * d;
    }
    float stdv = sqrtf(var * (1.0f / (M_ENS - 1)));  // ddof=1
    float ks = 3.3f * stdv;

    float pen = 0.0f;
    #pragma unroll
    for (int e = 0; e < M_ENS; ++e) {
        float dev = fabsf(x[e] - mean);
        float p = dev - ks;
        pen += (p > 0.0f) ? p : 0.0f;
    }

    // crps_px = dxy/m - tri/m^2 (diag zero); fold final coefficients now
    float s = (dxy * (1.0f / M_ENS) - tri * (1.0f / (M_ENS * M_ENS))) * (1.0f / BHWf)
            + pen * (0.02f / (BHWf * M_ENS));

    // wave64 shuffle reduce, then 4-entry LDS cross-wave reduce
    #pragma unroll
    for (int off = 32; off > 0; off >>= 1)
        s += __shfl_down(s, off, 64);

    __shared__ float sw[BLOCK / 64];
    __shared__ bool s_last;
    int wave = threadIdx.x >> 6;
    int lane = threadIdx.x & 63;
    if (lane == 0) sw[wave] = s;
    __syncthreads();
    if (threadIdx.x == 0) {
        float t = sw[0] + sw[1] + sw[2] + sw[3];
        int bid = blockIdx.y * BPI + blockIdx.x;
        partial[bid] = t;
        __threadfence();                              // publish partial (device scope)
        unsigned int old = atomicAdd(counter, 1u);
        // modular ticket: exactly one finisher per any run of NB increments,
        // regardless of the counter's starting value (poison-proof, reset-free)
        s_last = ((old + 1u) % (unsigned)NB == 0u);
    }
    __syncthreads();

    if (s_last) {                                     // uniform across block
        __threadfence();                              // acquire before reading partials
        float c = 0.0f;
        for (int i = threadIdx.x; i < NB; i += BLOCK) // fixed order -> deterministic
            c += partial[i];
        #pragma unroll
        for (int off = 32; off > 0; off >>= 1)
            c += __shfl_down(c, off, 64);
        if (lane == 0) sw[wave] = c;
        __syncthreads();
        if (threadIdx.x == 0)
            out[0] = sw[0] + sw[1] + sw[2] + sw[3];
    }
}

extern "C" void kernel_launch(void* const* d_in, const int* in_sizes, int n_in,
                              void* d_out, int out_size, void* d_ws, size_t ws_size,
                              hipStream_t stream) {
    const float* forecast = (const float*)d_in[0];
    const float* truth    = (const float*)d_in[1];
    float* out = (float*)d_out;
    float* partial = (float*)d_ws;                              // NB floats
    unsigned int* counter = (unsigned int*)((char*)d_ws + NB * sizeof(float));

    dim3 grid(BPI, 32);
    crps_onepass_kernel<<<grid, BLOCK, 0, stream>>>(forecast, truth, partial, counter, out);
}

// Round 7
// 12.148 us; speedup vs baseline: 2.4477x; 2.4477x over previous
//
#include <hip/hip_runtime.h>
#include <math.h>

// forecast (32,20,96,96) f32, truth (32,96,96) f32 -> scalar f32
#define M_ENS 20
#define HW    9216            // 96*96 pixels per image
#define BHWf  294912.0f
#define BLOCK 512
#define BPI   18              // blocks per image: 18*512 == 9216 exact
#define NB    576             // 18*32 total blocks

__global__ void __launch_bounds__(BLOCK)
crps_partial_kernel(const float* __restrict__ forecast,
                    const float* __restrict__ truth,
                    float* __restrict__ partial) {
    int b  = blockIdx.y;                             // image index 0..31
    int hw = blockIdx.x * BLOCK + threadIdx.x;       // pixel in image, exact cover
    float y = truth[b * HW + hw];                    // issue first (dxy dependency)

    const float* fp = forecast + (size_t)b * (M_ENS * HW) + hw;
    float x[M_ENS];
    #pragma unroll
    for (int e = 0; e < M_ENS; ++e) x[e] = fp[e * HW];

    float dxy = 0.0f, sum = 0.0f;
    #pragma unroll
    for (int e = 0; e < M_ENS; ++e) {
        dxy += fabsf(x[e] - y);
        sum += x[e];
    }

    float tri = 0.0f;                                // upper-triangle pair sum
    #pragma unroll
    for (int i = 0; i < M_ENS; ++i) {
        #pragma unroll
        for (int j = i + 1; j < M_ENS; ++j) {
            tri += fabsf(x[i] - x[j]);
        }
    }

    float mean = sum * (1.0f / M_ENS);
    float var = 0.0f;
    #pragma unroll
    for (int e = 0; e < M_ENS; ++e) {
        float d = x[e] - mean;
        var += d * d;
    }
    float stdv = sqrtf(var * (1.0f / (M_ENS - 1)));  // ddof=1
    float ks = 3.3f * stdv;

    // penalty: sum max(|d|-ks,0) = sum max3(d,-d,ks) - m*ks  (negate folds free)
    float pmax = 0.0f;
    #pragma unroll
    for (int e = 0; e < M_ENS; ++e) {
        float d = x[e] - mean;
        pmax += fmaxf(fmaxf(d, -d), ks);             // clang folds to v_max3
    }
    float pen = pmax - M_ENS * ks;

    // crps_px = dxy/m - tri/m^2 (diag zero); fold final coefficients now
    float s = (dxy * (1.0f / M_ENS) - tri * (1.0f / (M_ENS * M_ENS))) * (1.0f / BHWf)
            + pen * (0.02f / (BHWf * M_ENS));

    // wave64 shuffle reduce, then 8-entry LDS cross-wave reduce
    #pragma unroll
    for (int off = 32; off > 0; off >>= 1)
        s += __shfl_down(s, off, 64);

    __shared__ float sw[BLOCK / 64];
    int wave = threadIdx.x >> 6;
    int lane = threadIdx.x & 63;
    if (lane == 0) sw[wave] = s;
    __syncthreads();
    if (threadIdx.x == 0) {
        float t = sw[0];
        #pragma unroll
        for (int w = 1; w < BLOCK / 64; ++w) t += sw[w];
        partial[blockIdx.y * BPI + blockIdx.x] = t;
    }
}

__global__ void __launch_bounds__(64)
crps_final_kernel(const float* __restrict__ partial, float* __restrict__ out) {
    float s = 0.0f;
    #pragma unroll
    for (int i = 0; i < NB / 64; ++i)                // 9 strided loads, exact
        s += partial[i * 64 + threadIdx.x];
    #pragma unroll
    for (int off = 32; off > 0; off >>= 1)
        s += __shfl_down(s, off, 64);
    if (threadIdx.x == 0) out[0] = s;
}

extern "C" void kernel_launch(void* const* d_in, const int* in_sizes, int n_in,
                              void* d_out, int out_size, void* d_ws, size_t ws_size,
                              hipStream_t stream) {
    const float* forecast = (const float*)d_in[0];
    const float* truth    = (const float*)d_in[1];
    float* out = (float*)d_out;
    float* partial = (float*)d_ws;                   // NB floats = 2304 B

    dim3 grid(BPI, 32);
    crps_partial_kernel<<<grid, BLOCK, 0, stream>>>(forecast, truth, partial);
    crps_final_kernel<<<1, 64, 0, stream>>>(partial, out);
}

// Round 8
// 11.507 us; speedup vs baseline: 2.5840x; 1.0557x over previous
//
#include <hip/hip_runtime.h>
#include <math.h>

// forecast (32,20,96,96) f32, truth (32,96,96) f32 -> scalar f32
#define M_ENS 20
#define HW    9216            // 96*96 pixels per image
#define BHWf  294912.0f
#define BLOCK 256
#define BPI   36              // blocks per image: 36*256 == 9216 exact
#define NB    1152            // 36*32 total blocks

__global__ void __launch_bounds__(BLOCK)
crps_partial_kernel(const float* __restrict__ forecast,
                    const float* __restrict__ truth,
                    float* __restrict__ partial) {
    int b  = blockIdx.y;                             // image index 0..31
    int hw = blockIdx.x * BLOCK + threadIdx.x;       // pixel in image, exact cover
    float y = truth[b * HW + hw];                    // issue first (dxy dependency)

    const float* fp = forecast + (size_t)b * (M_ENS * HW) + hw;
    float x[M_ENS];
    #pragma unroll
    for (int e = 0; e < M_ENS; ++e) x[e] = fp[e * HW];

    float dxy = 0.0f, sum = 0.0f;
    #pragma unroll
    for (int e = 0; e < M_ENS; ++e) {
        dxy += fabsf(x[e] - y);
        sum += x[e];
    }

    float tri = 0.0f;                                // upper-triangle pair sum
    #pragma unroll
    for (int i = 0; i < M_ENS; ++i) {
        #pragma unroll
        for (int j = i + 1; j < M_ENS; ++j) {
            tri += fabsf(x[i] - x[j]);
        }
    }

    float mean = sum * (1.0f / M_ENS);
    float var = 0.0f;
    #pragma unroll
    for (int e = 0; e < M_ENS; ++e) {
        float d = x[e] - mean;
        var += d * d;
    }
    float stdv = sqrtf(var * (1.0f / (M_ENS - 1)));  // ddof=1
    float ks = 3.3f * stdv;

    // penalty: sum max(|d|-ks,0) = sum max3(d,-d,ks) - m*ks (abs/neg fold free)
    float pmax = 0.0f;
    #pragma unroll
    for (int e = 0; e < M_ENS; ++e) {
        float d = x[e] - mean;
        pmax += fmaxf(fmaxf(d, -d), ks);             // clang folds to v_max3
    }
    float pen = pmax - M_ENS * ks;

    // crps_px = dxy/m - tri/m^2 (diag zero); fold final coefficients now
    float s = (dxy * (1.0f / M_ENS) - tri * (1.0f / (M_ENS * M_ENS))) * (1.0f / BHWf)
            + pen * (0.02f / (BHWf * M_ENS));

    // wave64 shuffle reduce, then 4-entry LDS cross-wave reduce
    #pragma unroll
    for (int off = 32; off > 0; off >>= 1)
        s += __shfl_down(s, off, 64);

    __shared__ float sw[BLOCK / 64];
    int wave = threadIdx.x >> 6;
    int lane = threadIdx.x & 63;
    if (lane == 0) sw[wave] = s;
    __syncthreads();
    if (threadIdx.x == 0) {
        float t = sw[0] + sw[1] + sw[2] + sw[3];
        partial[blockIdx.y * BPI + blockIdx.x] = t;
    }
}

__global__ void __launch_bounds__(64)
crps_final_kernel(const float* __restrict__ partial, float* __restrict__ out) {
    float s = 0.0f;
    #pragma unroll
    for (int i = 0; i < NB / 64; ++i)                // 18 strided loads, exact
        s += partial[i * 64 + threadIdx.x];
    #pragma unroll
    for (int off = 32; off > 0; off >>= 1)
        s += __shfl_down(s, off, 64);
    if (threadIdx.x == 0) out[0] = s;
}

extern "C" void kernel_launch(void* const* d_in, const int* in_sizes, int n_in,
                              void* d_out, int out_size, void* d_ws, size_t ws_size,
                              hipStream_t stream) {
    const float* forecast = (const float*)d_in[0];
    const float* truth    = (const float*)d_in[1];
    float* out = (float*)d_out;
    float* partial = (float*)d_ws;                   // NB floats = 4608 B

    dim3 grid(BPI, 32);
    crps_partial_kernel<<<grid, BLOCK, 0, stream>>>(forecast, truth, partial);
    crps_final_kernel<<<1, 64, 0, stream>>>(partial, out);
}